// Round 3
// baseline (588.706 us; speedup 1.0000x reference)
//
#include <hip/hip_runtime.h>

#define NB 16
#define NT 16384
#define ND 256
#define NS 4
#define SLICES 16
#define TPB 1024            // tokens per block (one slice)
#define CHUNK 128           // tokens per K-iteration (16 waves x 8)
#define NITER (TPB / CHUNK) // 8

typedef float f32x4 __attribute__((ext_vector_type(4)));
typedef short s16x8 __attribute__((ext_vector_type(8)));

__device__ __forceinline__ unsigned short f2bf(float f) {
  unsigned int u = __float_as_uint(f);
  return (unsigned short)((u + 0x7FFFu + ((u >> 16) & 1u)) >> 16);
}

// Raw barriers (no compiler vmcnt(0) drain) so register prefetch of the next
// chunk stays in flight across the MFMA phase. bar1 needs lgkmcnt(0) so our
// ds_writes are visible; bar2 needs nothing extra (frag reads were consumed
// by MFMAs, which forced their lgkm waits).
#define BAR_LGKM() asm volatile("s_waitcnt lgkmcnt(0)\n\ts_barrier" ::: "memory")
#define BAR_RAW()  asm volatile("s_barrier" ::: "memory")

// One block = one (batch, slice of 1024 tokens), 16 waves.
// Wave w is both producer (writes token-group w of each chunk) and consumer
// (Gram tile r=w>>2, c=w&3 of 64x64). Producer lane owns dims 4l..4l+3 of 8
// consecutive tokens -> pack is in-lane, transpose is free.
__global__ __launch_bounds__(1024) void fused_gram(
    const float* __restrict__ emb, const float* __restrict__ lab,
    float* __restrict__ P, float* __restrict__ PY, float* __restrict__ CntP)
{
  const int tid  = threadIdx.x;
  const int lane = tid & 63;
  const int w    = tid >> 6;           // wave 0..15
  const int b     = blockIdx.x >> 4;
  const int slice = blockIdx.x & 15;

  // K-blocked bf16 chunk: [kk(4)][qs(4)][d(256)][tok(8)] u16 = 64 KB.
  // Note (kk*4+qs) == producer wave id.
  __shared__ __align__(16) unsigned short blkT[4 * 4 * ND * 8];
  // Y B-fragments: [step(32)][lane(64)][8] u16 = 32 KB (step = it*4+kk).
  __shared__ __align__(16) unsigned short Yf[32 * 64 * 8];
  __shared__ unsigned int spk2[64];    // 2-bit speaker ids, 16 tokens/word
  __shared__ float cnt_l[NS];

  if (tid < 64) spk2[tid] = 0u;
  if (tid < NS) cnt_l[tid] = 0.0f;

  const float* embB  = emb + ((size_t)b * NT + slice * TPB) * ND;
  const float* wbase = embB + (size_t)(w * 8) * ND + 4 * lane;

  // issue chunk-0 batch-A loads early (complete by prologue's end; free)
  f32x4 pf[4];
  #pragma unroll
  for (int j = 0; j < 4; ++j)
    pf[j] = *(const f32x4*)(wbase + (size_t)j * ND);

  __syncthreads();

  // --- speaker decode: thread i owns token i ---
  {
    f32x4 y = ((const f32x4*)(lab + ((size_t)b * NT + slice * TPB) * NS))[tid];
    int s = (int)(y.y + 2.0f * y.z + 3.0f * y.w + 0.5f);
    atomicOr(&spk2[tid >> 4], (unsigned)s << (2 * (tid & 15)));
    unsigned long long m0 = __ballot(s == 0);
    unsigned long long m1 = __ballot(s == 1);
    unsigned long long m2 = __ballot(s == 2);
    unsigned long long m3 = __ballot(s == 3);
    if (lane == 0) {
      atomicAdd(&cnt_l[0], (float)__popcll(m0));
      atomicAdd(&cnt_l[1], (float)__popcll(m1));
      atomicAdd(&cnt_l[2], (float)__popcll(m2));
      atomicAdd(&cnt_l[3], (float)__popcll(m3));
    }
  }
  __syncthreads();

  // --- build Y fragments once: 2 rows per thread ---
  #pragma unroll
  for (int rr2 = 0; rr2 < 2; ++rr2) {
    int rho  = tid * 2 + rr2;            // 0..2047
    int step = rho >> 6, ln = rho & 63;  // step = it*4+kk
    int q = ln >> 4, col = ln & 15;
    unsigned wv = spk2[step * 2 + (q >> 1)];
    int base = (q & 1) * 16;
    s16x8 y8;
    #pragma unroll
    for (int j = 0; j < 8; ++j) {
      int sp = (int)((wv >> (base + 2 * j)) & 3u);
      y8[j] = (sp == col) ? (short)0x3F80 : (short)0;
    }
    ((s16x8*)Yf)[rho] = y8;
  }
  __syncthreads();

  const int r = w >> 2, c = w & 3;
  const int quad = lane >> 4, m16 = lane & 15;

  f32x4 acc[4][4];
  f32x4 yacc = (f32x4){0.f, 0.f, 0.f, 0.f};
  #pragma unroll
  for (int i = 0; i < 4; ++i)
    #pragma unroll
    for (int j = 0; j < 4; ++j) acc[i][j] = (f32x4){0.f, 0.f, 0.f, 0.f};

  const s16x8* bp = (const s16x8*)blkT;
  const s16x8* yp = (const s16x8*)Yf;
  s16x8* wp = (s16x8*)blkT;

  for (int it = 0; it < NITER; ++it) {
    const float* ib = wbase + (size_t)it * CHUNK * ND;

    // ---- phase N: issue batch B, normalize 8 tokens, pack, write blkT ----
    f32x4 vb[4];
    #pragma unroll
    for (int j = 0; j < 4; ++j)
      vb[j] = *(const f32x4*)(ib + (size_t)(4 + j) * ND);

    unsigned short sv[8][4];
    #pragma unroll
    for (int j = 0; j < 8; ++j) {
      f32x4 v = (j < 4) ? pf[j] : vb[j - 4];
      float ss = fmaf(v.x, v.x, fmaf(v.y, v.y, fmaf(v.z, v.z, v.w * v.w)));
      #pragma unroll
      for (int off = 32; off; off >>= 1) ss += __shfl_xor(ss, off);
      float sc = 1.0f / fmaxf(sqrtf(ss), 1e-12f);
      sv[j][0] = f2bf(v.x * sc); sv[j][1] = f2bf(v.y * sc);
      sv[j][2] = f2bf(v.z * sc); sv[j][3] = f2bf(v.w * sc);
    }
    #pragma unroll
    for (int q = 0; q < 4; ++q) {
      s16x8 row;
      #pragma unroll
      for (int j = 0; j < 8; ++j) row[j] = (short)sv[j][q];
      wp[w * ND + 4 * lane + q] = row;   // [(kk*4+qs)==w][d][8tok]
    }

    // prefetch next chunk's batch A — stays in flight across bar1 + M
    if (it + 1 < NITER) {
      const float* nb = wbase + (size_t)(it + 1) * CHUNK * ND;
      #pragma unroll
      for (int j = 0; j < 4; ++j)
        pf[j] = *(const f32x4*)(nb + (size_t)j * ND);
    }

    BAR_LGKM();   // ds_writes visible; vmcnt NOT drained

    // ---- phase M: K=128 as 4 x K=32 MFMA steps ----
    #pragma unroll
    for (int kk = 0; kk < 4; ++kk) {
      const int kb = (kk * 4 + quad) * ND;
      s16x8 afr[4];
      #pragma unroll
      for (int mi = 0; mi < 4; ++mi)
        afr[mi] = bp[kb + r * 64 + mi * 16 + m16];

      s16x8 yfr = yp[(it * 4 + kk) * 64 + lane];
      yacc = __builtin_amdgcn_mfma_f32_16x16x32_bf16(afr[c], yfr, yacc, 0, 0, 0);

      #pragma unroll
      for (int nj = 0; nj < 4; ++nj) {
        s16x8 bfr = bp[kb + c * 64 + nj * 16 + m16];
        #pragma unroll
        for (int mi = 0; mi < 4; ++mi)
          acc[mi][nj] = __builtin_amdgcn_mfma_f32_16x16x32_bf16(afr[mi], bfr, acc[mi][nj], 0, 0, 0);
      }
    }

    BAR_RAW();    // protect blkT before next N writes
  }

  // ---- epilogue: coalesced stores of partial Gram ----
  {
    float* Pb = P + ((size_t)blockIdx.x << 16);
    #pragma unroll
    for (int mi = 0; mi < 4; ++mi)
      #pragma unroll
      for (int nj = 0; nj < 4; ++nj)
        #pragma unroll
        for (int rr = 0; rr < 4; ++rr) {
          int row = r * 64 + mi * 16 + quad * 4 + rr;  // C/D: row = quad*4+reg
          int col = c * 64 + nj * 16 + m16;            //      col = lane&15
          Pb[row * ND + col] = acc[mi][nj][rr];
        }
    float* PYb = PY + ((size_t)blockIdx.x << 12);
    #pragma unroll
    for (int rr = 0; rr < 4; ++rr)
      PYb[(w * 16 + quad * 4 + rr) * 16 + m16] = yacc[rr];
    if (tid < NS) CntP[blockIdx.x * NS + tid] = cnt_l[tid];
  }
}

// loss = sum_b [ sum(sum_s P)^2 - 2 sum(sum_s PY)^2 + sum(sum_s Cnt)^2 ] / (T*T*B)
__global__ __launch_bounds__(256) void finalize_kernel(
    const float* __restrict__ P, const float* __restrict__ PY,
    const float* __restrict__ CntP, float* __restrict__ out)
{
  const int b = blockIdx.x >> 4, seg = blockIdx.x & 15;
  const int tid = threadIdx.x;
  float local = 0.f;

  const float* Pb = P + ((size_t)b * 16) * 65536 + seg * 4096;
  #pragma unroll 4
  for (int k = 0; k < 16; ++k) {
    int e = tid + k * 256;
    float g = 0.f;
    #pragma unroll
    for (int s = 0; s < 16; ++s) g += Pb[(size_t)s * 65536 + e];
    local = fmaf(g, g, local);
  }
  if (seg == 0) {
    const float* Yb = PY + ((size_t)b * 16) * 4096;
    #pragma unroll 4
    for (int k = 0; k < 16; ++k) {
      int e = tid + k * 256;
      float g = 0.f;
      #pragma unroll
      for (int s = 0; s < 16; ++s) g += Yb[(size_t)s * 4096 + e];
      local = fmaf(-2.f * g, g, local);   // cols 4..15 are exactly 0
    }
    if (tid < NS) {
      float ct = 0.f;
      for (int s = 0; s < 16; ++s) ct += CntP[(b * 16 + s) * NS + tid];
      local = fmaf(ct, ct, local);
    }
  }
  #pragma unroll
  for (int off = 32; off; off >>= 1) local += __shfl_xor(local, off);
  __shared__ float wsum[4];
  if ((tid & 63) == 0) wsum[tid >> 6] = local;
  __syncthreads();
  if (tid == 0) {
    float s = wsum[0] + wsum[1] + wsum[2] + wsum[3];
    atomicAdd(out, s * (1.0f / 4294967296.0f));  // T*T*B = 2^32 exact
  }
}

extern "C" void kernel_launch(void* const* d_in, const int* in_sizes, int n_in,
                              void* d_out, int out_size, void* d_ws, size_t ws_size,
                              hipStream_t stream) {
  const float* emb = (const float*)d_in[0];  // [16,16384,256] fp32
  const float* lab = (const float*)d_in[1];  // [16,16384,4] fp32 one-hot
  float* out = (float*)d_out;

  float* P    = (float*)d_ws;                         // 256 * 65536 f32 = 64 MB
  float* PY   = P + (size_t)256 * 65536;              // 256 * 4096 f32 = 4 MB
  float* CntP = PY + (size_t)256 * 4096;              // 256 * 4 f32

  hipMemsetAsync(d_out, 0, sizeof(float), stream);

  fused_gram<<<dim3(NB * SLICES), dim3(1024), 0, stream>>>(emb, lab, P, PY, CntP);
  finalize_kernel<<<dim3(NB * SLICES), dim3(256), 0, stream>>>(P, PY, CntP, out);
}